// Round 1
// baseline (5473.675 us; speedup 1.0000x reference)
//
#include <hip/hip_runtime.h>
#include <hip/hip_bf16.h>

#define T_SEQ 256
#define BATCH 256
#define HID   1024
#define EMB   10
#define VOCABN 10
#define NCLS  10

typedef __attribute__((ext_vector_type(8))) short short8;
typedef __attribute__((ext_vector_type(4))) float floatx4;

// ---- workspace layout (bytes) ----
#define OFF_WHB   0                          // 4096*1024 bf16 = 8 MB
#define OFF_PTAB  (8*1024*1024)              // 10*4096 f32    = 160 KB
#define OFF_H0    (OFF_PTAB + VOCABN*4*HID*4)      // 256*1024 bf16 = 512 KB
#define OFF_H1    (OFF_H0 + BATCH*HID*2)           // 512 KB
#define OFF_C     (OFF_H1 + BATCH*HID*2)           // 256*1024 f32 = 1 MB

__device__ __forceinline__ float fsig(float x) {
    return __builtin_amdgcn_rcpf(1.0f + __expf(-x));
}
__device__ __forceinline__ float ftanh(float x) {
    return 2.0f * fsig(2.0f * x) - 1.0f;
}

// One-shot prep: cast Wh(4x 1024x1024) -> bf16 gate-major; build ptab; zero h0,c.
__global__ __launch_bounds__(256)
void prep_kernel(const float* __restrict__ Wgh, const float* __restrict__ Wih,
                 const float* __restrict__ Wfh, const float* __restrict__ Woh,
                 const float* __restrict__ embed,
                 const float* __restrict__ Wgx, const float* __restrict__ Wix,
                 const float* __restrict__ Wfx, const float* __restrict__ Wox,
                 const float* __restrict__ bg, const float* __restrict__ bi,
                 const float* __restrict__ bf, const float* __restrict__ bo,
                 __hip_bfloat16* __restrict__ whb, float* __restrict__ ptab,
                 __hip_bfloat16* __restrict__ h0, float* __restrict__ c)
{
    int idx = blockIdx.x * 256 + threadIdx.x;   // 0 .. 4194303
    {
        int gate = idx >> 20;
        int rem  = idx & 0xFFFFF;
        const float* W = (gate == 0) ? Wgh : (gate == 1) ? Wih : (gate == 2) ? Wfh : Woh;
        whb[idx] = __float2bfloat16(W[rem]);
    }
    if (idx < VOCABN * 4 * HID) {               // 40960: ptab[v*4096 + g]
        int v = idx >> 12;
        int g = idx & 4095;
        int gg = g >> 10;
        int j  = g & 1023;
        const float* Wx = (gg == 0) ? Wgx : (gg == 1) ? Wix : (gg == 2) ? Wfx : Wox;
        const float* bb = (gg == 0) ? bg  : (gg == 1) ? bi  : (gg == 2) ? bf  : bo;
        float s = bb[j];
        #pragma unroll
        for (int e = 0; e < EMB; ++e) s += embed[v * EMB + e] * Wx[j * EMB + e];
        ptab[idx] = s;
    }
    if (idx < BATCH * HID) {
        c[idx]  = 0.0f;
        h0[idx] = __float2bfloat16(0.0f);
    }
}

// One timestep: z = ptab[x[:,t]] + h_in @ Wh^T ; gates ; update c ; write h_out.
// Grid: 256 WGs = 64 hidden-tiles (16 hidden each -> 64 gate-rows) x 4 batch-tiles (64 batches).
// 4 waves/WG; wave w owns batches b0+16w..+16. MFMA 16x16x32 bf16.
__global__ __launch_bounds__(256)
void step_kernel(const int* __restrict__ x, const float* __restrict__ ptab,
                 const __hip_bfloat16* __restrict__ whb,
                 const __hip_bfloat16* __restrict__ hin,
                 __hip_bfloat16* __restrict__ hout,
                 float* __restrict__ c, int tstep)
{
    const int ht = blockIdx.x & 63;
    const int bt = blockIdx.x >> 6;
    const int j0 = ht << 4;          // first hidden unit of this tile
    const int b0 = bt << 6;          // first batch of this tile
    const int tid  = threadIdx.x;
    const int w    = tid >> 6;
    const int lane = tid & 63;
    const int l16  = lane & 15;
    const int quad = lane >> 4;

    // Fragment base pointers (16B aligned).
    const short* A  = (const short*)hin + (((size_t)(b0 + (w << 4) + l16)) << 10) + (quad << 3);
    const short* B0 = (const short*)whb + (((size_t)(j0 + l16)) << 10) + (quad << 3);

    // Init accumulators from the input-projection table (bias folded in).
    const int bq  = b0 + (w << 4) + (quad << 2);   // D row = quad*4 + r  -> batch bq+r
    const int col = j0 + l16;                      // D col = l16         -> hidden j0+l16
    int xv[4];
    #pragma unroll
    for (int r = 0; r < 4; ++r) xv[r] = x[(bq + r) * T_SEQ + tstep];

    floatx4 acc0, acc1, acc2, acc3;
    #pragma unroll
    for (int r = 0; r < 4; ++r) {
        const float* p = ptab + xv[r] * 4096 + col;
        acc0[r] = p[0];
        acc1[r] = p[1024];
        acc2[r] = p[2048];
        acc3[r] = p[3072];
    }

    // K loop: 32 chunks of 32. B n-tiles are the 4 gates for hidden slice j0..j0+16.
    #pragma unroll 2
    for (int k0 = 0; k0 < HID; k0 += 32) {
        short8 a  = *(const short8*)(A + k0);
        short8 vg = *(const short8*)(B0 + k0);
        short8 vi = *(const short8*)(B0 + (1 << 20) + k0);
        short8 vf = *(const short8*)(B0 + (2 << 20) + k0);
        short8 vo = *(const short8*)(B0 + (3 << 20) + k0);
        acc0 = __builtin_amdgcn_mfma_f32_16x16x32_bf16(a, vg, acc0, 0, 0, 0);
        acc1 = __builtin_amdgcn_mfma_f32_16x16x32_bf16(a, vi, acc1, 0, 0, 0);
        acc2 = __builtin_amdgcn_mfma_f32_16x16x32_bf16(a, vf, acc2, 0, 0, 0);
        acc3 = __builtin_amdgcn_mfma_f32_16x16x32_bf16(a, vo, acc3, 0, 0, 0);
    }

    // Gates + state update (WG-local ownership of (batch, hidden) pairs).
    #pragma unroll
    for (int r = 0; r < 4; ++r) {
        float zg = acc0[r], zi = acc1[r], zf = acc2[r], zo = acc3[r];
        int off = ((bq + r) << 10) + col;
        float cold = c[off];
        float gv = ftanh(zg);
        float iv = fsig(zi);
        float fv = fsig(zf);
        float ov = fsig(zo);
        float cn = gv * iv + cold * fv;
        c[off] = cn;
        hout[off] = __float2bfloat16(ftanh(cn) * ov);
    }
}

// y = h @ W_ph^T + b_p : one wave per batch row.
__global__ __launch_bounds__(256)
void final_kernel(const __hip_bfloat16* __restrict__ h, const float* __restrict__ Wph,
                  const float* __restrict__ bp, float* __restrict__ y)
{
    int w = threadIdx.x >> 6;
    int lane = threadIdx.x & 63;
    int b = blockIdx.x * 4 + w;
    float acc[NCLS];
    #pragma unroll
    for (int k = 0; k < NCLS; ++k) acc[k] = 0.0f;
    for (int k = lane; k < HID; k += 64) {
        float hv = __bfloat162float(h[b * HID + k]);
        #pragma unroll
        for (int cls = 0; cls < NCLS; ++cls) acc[cls] += hv * Wph[cls * HID + k];
    }
    #pragma unroll
    for (int cls = 0; cls < NCLS; ++cls) {
        float v = acc[cls];
        #pragma unroll
        for (int off = 32; off > 0; off >>= 1) v += __shfl_down(v, off);
        if (lane == 0) y[b * NCLS + cls] = v + bp[cls];
    }
}

extern "C" void kernel_launch(void* const* d_in, const int* in_sizes, int n_in,
                              void* d_out, int out_size, void* d_ws, size_t ws_size,
                              hipStream_t stream)
{
    const int*   x     = (const int*)d_in[0];
    const float* embed = (const float*)d_in[1];
    const float* Wgx   = (const float*)d_in[2];
    const float* Wix   = (const float*)d_in[3];
    const float* Wfx   = (const float*)d_in[4];
    const float* Wox   = (const float*)d_in[5];
    const float* Wgh   = (const float*)d_in[6];
    const float* Wih   = (const float*)d_in[7];
    const float* Wfh   = (const float*)d_in[8];
    const float* Woh   = (const float*)d_in[9];
    const float* Wph   = (const float*)d_in[10];
    const float* bg    = (const float*)d_in[11];
    const float* bi    = (const float*)d_in[12];
    const float* bf    = (const float*)d_in[13];
    const float* bo    = (const float*)d_in[14];
    const float* bp    = (const float*)d_in[15];
    float* out = (float*)d_out;

    char* ws = (char*)d_ws;
    __hip_bfloat16* whb  = (__hip_bfloat16*)(ws + OFF_WHB);
    float*          ptab = (float*)(ws + OFF_PTAB);
    __hip_bfloat16* h0   = (__hip_bfloat16*)(ws + OFF_H0);
    __hip_bfloat16* h1   = (__hip_bfloat16*)(ws + OFF_H1);
    float*          c    = (float*)(ws + OFF_C);

    prep_kernel<<<16384, 256, 0, stream>>>(Wgh, Wih, Wfh, Woh, embed,
                                           Wgx, Wix, Wfx, Wox,
                                           bg, bi, bf, bo,
                                           whb, ptab, h0, c);

    for (int t = 0; t < T_SEQ; ++t) {
        const __hip_bfloat16* hin = (t & 1) ? h1 : h0;
        __hip_bfloat16*      hout = (t & 1) ? h0 : h1;
        step_kernel<<<256, 256, 0, stream>>>(x, ptab, whb, hin, hout, c, t);
    }

    // T=256 even -> final h lives in h0.
    final_kernel<<<64, 256, 0, stream>>>(h0, Wph, bp, out);
}